// Round 19
// baseline (520.835 us; speedup 1.0000x reference)
//
#include <hip/hip_runtime.h>
#include <hip/hip_bf16.h>
#include <hip/hip_fp16.h>

#define NN 80000
#define NE 1280000
#define NL 4
#define NG 256

typedef __attribute__((ext_vector_type(8))) _Float16 half8;
typedef __attribute__((ext_vector_type(4))) float f32x4;

__device__ __forceinline__ float wave_sum(float v) {
    for (int off = 32; off; off >>= 1) v += __shfl_xor(v, off, 64);
    return v;
}

// ---------------- CSR build ----------------
__global__ void k_count(const int* __restrict__ idx, int* __restrict__ cnt) {
    int e = blockIdx.x * 256 + threadIdx.x;
    if (e < NE) atomicAdd(&cnt[idx[e]], 1);
}

__global__ void k_scan1(const int* __restrict__ in, int* __restrict__ out,
                        int* __restrict__ bsum, int n) {
    __shared__ int ws[4];
    int i = blockIdx.x * 256 + threadIdx.x;
    int v = (i < n) ? in[i] : 0;
    int lane = threadIdx.x & 63, w = threadIdx.x >> 6;
    for (int off = 1; off < 64; off <<= 1) {
        int t = __shfl_up(v, off, 64);
        if (lane >= off) v += t;
    }
    if (lane == 63) ws[w] = v;
    __syncthreads();
    if (threadIdx.x == 0) {
        int acc = 0;
        for (int k = 0; k < 4; k++) { int t = ws[k]; ws[k] = acc; acc += t; }
    }
    __syncthreads();
    v += ws[w];
    if (i < n) out[i] = v;
    if (threadIdx.x == 255) bsum[blockIdx.x] = v;
}

__global__ void k_scan2(int* __restrict__ bsum, int nb) {
    __shared__ int ws[4];
    __shared__ int carry;
    if (threadIdx.x == 0) carry = 0;
    __syncthreads();
    for (int base = 0; base < nb; base += 256) {
        int i = base + threadIdx.x;
        int v = (i < nb) ? bsum[i] : 0;
        int lane = threadIdx.x & 63, w = threadIdx.x >> 6;
        for (int off = 1; off < 64; off <<= 1) {
            int t = __shfl_up(v, off, 64);
            if (lane >= off) v += t;
        }
        if (lane == 63) ws[w] = v;
        __syncthreads();
        if (threadIdx.x == 0) {
            int acc = carry;
            for (int k = 0; k < 4; k++) { int t = ws[k]; ws[k] = acc; acc += t; }
            carry = acc;
        }
        __syncthreads();
        v += ws[w];
        if (i < nb) bsum[i] = v;
        __syncthreads();
    }
}

__global__ void k_scan3(int* __restrict__ rowptr, const int* __restrict__ bsum, int n) {
    int i = blockIdx.x * 256 + threadIdx.x;
    if (i < n) {
        int off = (blockIdx.x > 0) ? bsum[blockIdx.x - 1] : 0;
        rowptr[1 + i] += off;
    }
    if (i == 0 && blockIdx.x == 0) rowptr[0] = 0;
}

// Partitioned fill (R18-proven): partition p = blockIdx.x & 7 handles dst in
// [p*10000,(p+1)*10000) -> csr32 writes stay in an L2-resident window.
__global__ void k_fill(const int* __restrict__ src, const int* __restrict__ dst,
                       const int* __restrict__ eattr, const int* __restrict__ rowptr,
                       int* __restrict__ wofs, int* __restrict__ csr32) {
    int part = blockIdx.x & 7;
    int e = (blockIdx.x >> 3) * 256 + threadIdx.x;
    if (e >= NE) return;
    int d = dst[e];
    if (d / 10000 != part) return;
    int pos = rowptr[d] + atomicAdd(&wofs[d], 1);
    int a0 = eattr[e * 3], a1 = eattr[e * 3 + 1], a2 = eattr[e * 3 + 2];
    csr32[pos] = (src[e] << 10) | (a0 + a1 * 10 + a2 * 100);
}

// ---------------- fused prep: comb + packw + bounds ----------------
__global__ void k_prep(const float* __restrict__ bond_emb, __half* __restrict__ comb,
                       const float* __restrict__ W1, const float* __restrict__ W2,
                       __half* __restrict__ w1t, __half* __restrict__ w2t,
                       const int* __restrict__ batch, int* __restrict__ gstart) {
    int idx = blockIdx.x * 256 + threadIdx.x;
    if (idx < NN) {
        int b = batch[idx];
        if (idx == 0) {
            for (int g = 0; g <= b; ++g) gstart[g] = 0;
        } else {
            int pb = batch[idx - 1];
            for (int g = pb + 1; g <= b; ++g) gstart[g] = idx;
        }
        if (idx == NN - 1) {
            for (int g = b + 1; g <= NG; ++g) gstart[g] = NN;
        }
    }
    if (idx < 64000) {
        int wid = idx >> 6, lane = idx & 63;
        int a0 = wid % 10, a1 = (wid / 10) % 10, a2 = wid / 100;
        comb[wid * 64 + lane] = __float2half(bond_emb[a0 * 64 + lane] +
                                             bond_emb[(10 + a1) * 64 + lane] +
                                             bond_emb[(20 + a2) * 64 + lane]);
    }
    if (idx < NL * 8192) {
        int l = idx >> 13, r = idx & 8191;
        int n1 = r >> 6, k1 = r & 63;
        w1t[idx] = __float2half(W1[(l * 64 + k1) * 128 + n1]);
        int n2 = r >> 7, k2 = r & 127;
        w2t[idx] = __float2half(W2[(l * 128 + k2) * 64 + n2]);
    }
}

__global__ void k_atom(const int* __restrict__ x, const float* __restrict__ atom_emb,
                       __half* __restrict__ xn) {
    int wid = (blockIdx.x * 256 + threadIdx.x) >> 6;
    int lane = threadIdx.x & 63;
    if (wid >= NN) return;
    float acc = 0.f;
#pragma unroll
    for (int f = 0; f < 9; f++) {
        int idx = x[wid * 9 + f] + f * 100;
        acc += atom_emb[idx * 64 + lane];
    }
    xn[wid * 64 + lane] = __float2half(acc);
}

// ---------------- FUSED conv: agg (4 waves x 4 nodes) -> LDS -> MFMA MLP (wave 0) ----
// NOTE: writes hh while other blocks gather hin -> hh must NOT alias hin (ping-pong).
__global__ __launch_bounds__(256) void k_conv(
    const __half* __restrict__ hin, const int* __restrict__ rowptr,
    const int* __restrict__ csr32, const __half* __restrict__ comb,
    const float* __restrict__ t, int l,
    const __half* __restrict__ w1t, const __half* __restrict__ w2t,
    const float* __restrict__ b1, const float* __restrict__ g1,
    const float* __restrict__ bb1, const float* __restrict__ b2,
    float* __restrict__ cur, int residual,
    __half* __restrict__ hh, const float* __restrict__ ng, const float* __restrict__ nbv) {
    __shared__ __half o_tile[16][136];   // padded rows: 272B -> 2-way bank alias max
    __shared__ __half midL[16][136];
    int w = threadIdx.x >> 6, lane = threadIdx.x & 63;
    int node0 = blockIdx.x * 16;         // NN == 5000*16
    int half = lane >> 5, lc = lane & 31;
    float tl = t[l];
    const __half2* hin2 = (const __half2*)hin;
    const __half2* comb2 = (const __half2*)comb;

    // ---- agg phase: each wave covers 4 nodes (2 passes x 2 half-waves) ----
#pragma unroll
    for (int pass = 0; pass < 2; ++pass) {
        int nb0 = w * 4 + pass * 2;              // in-block node pair base
        int ni = nb0 + half;
        int node = node0 + ni;
        __half2 hr2 = hin2[(long)node * 32 + lc];
        int rs0 = rowptr[node0 + nb0], mid = rowptr[node0 + nb0 + 1],
            re1 = rowptr[node0 + nb0 + 2];
        int base = half ? mid : rs0;
        int cnt = half ? (re1 - mid) : (mid - rs0);
        int cmax = max(mid - rs0, re1 - mid);
        float den0 = 0.f, den1 = 0.f, num0 = 0.f, num1 = 0.f;
#pragma unroll 4
        for (int i = 0; i < cmax; ++i) {
            bool valid = i < cnt;
            int v = csr32[valid ? base + i : 0];
            __half2 h2 = hin2[(long)(v >> 10) * 32 + lc];
            __half2 c2 = comb2[(v & 1023) * 32 + lc];
            __half2 s2 = __hadd2(h2, c2);
            float m0 = fmaxf(__low2float(s2), 0.f) + 1e-7f;
            float m1 = fmaxf(__high2float(s2), 0.f) + 1e-7f;
            float e0 = valid ? __expf(m0 * tl) : 0.f;
            float e1 = valid ? __expf(m1 * tl) : 0.f;
            den0 += e0; num0 = fmaf(e0, m0, num0);
            den1 += e1; num1 = fmaf(e1, m1, num1);
        }
        float r0 = num0 / (den0 + 1e-16f) + __low2float(hr2);
        float r1 = num1 / (den1 + 1e-16f) + __high2float(hr2);
        ((__half2*)&o_tile[ni][0])[lc] = __floats2half2_rn(r0, r1);
    }
    __syncthreads();
    if (w != 0) return;

    // ---- MLP phase (wave 0, R13-proven body; A-fragments from LDS) ----
    int lm = lane & 15, lh = lane >> 4;
    const __half* ob = &o_tile[lm][lh * 8];
    half8 a0 = *(const half8*)(ob);
    half8 a1 = *(const half8*)(ob + 32);
    const __half* w1b = w1t + l * 8192 + lm * 64 + lh * 8;
    f32x4 acc[8];
#pragma unroll
    for (int nb = 0; nb < 8; ++nb) {
        f32x4 c = {0.f, 0.f, 0.f, 0.f};
        half8 b0 = *(const half8*)(w1b + nb * 1024);
        half8 bx = *(const half8*)(w1b + nb * 1024 + 32);
        c = __builtin_amdgcn_mfma_f32_16x16x32_f16(a0, b0, c, 0, 0, 0);
        c = __builtin_amdgcn_mfma_f32_16x16x32_f16(a1, bx, c, 0, 0, 0);
        acc[nb] = c;
    }

    float bv[8], gv[8], bbv[8];
#pragma unroll
    for (int nb = 0; nb < 8; ++nb) {
        int n = l * 128 + nb * 16 + lm;
        bv[nb] = b1[n]; gv[nb] = g1[n]; bbv[nb] = bb1[n];
    }
    float ps[4] = {0.f, 0.f, 0.f, 0.f};
#pragma unroll
    for (int nb = 0; nb < 8; ++nb)
#pragma unroll
        for (int r = 0; r < 4; ++r) { acc[nb][r] += bv[nb]; ps[r] += acc[nb][r]; }
#pragma unroll
    for (int r = 0; r < 4; ++r) {
        for (int off = 1; off < 16; off <<= 1) ps[r] += __shfl_xor(ps[r], off, 64);
        ps[r] *= (1.f / 128.f);
    }
    float pv[4] = {0.f, 0.f, 0.f, 0.f};
#pragma unroll
    for (int nb = 0; nb < 8; ++nb)
#pragma unroll
        for (int r = 0; r < 4; ++r) { float d = acc[nb][r] - ps[r]; pv[r] = fmaf(d, d, pv[r]); }
#pragma unroll
    for (int r = 0; r < 4; ++r) {
        for (int off = 1; off < 16; off <<= 1) pv[r] += __shfl_xor(pv[r], off, 64);
        pv[r] = rsqrtf(pv[r] * (1.f / 128.f) + 1e-5f);
    }
#pragma unroll
    for (int nb = 0; nb < 8; ++nb)
#pragma unroll
        for (int r = 0; r < 4; ++r) {
            float m = fmaxf((acc[nb][r] - ps[r]) * pv[r] * gv[nb] + bbv[nb], 0.f);
            midL[lh * 4 + r][nb * 16 + lm] = __float2half(m);
        }

    const __half* mrow = &midL[lm][lh * 8];
    const __half* w2b = w2t + l * 8192 + lm * 128 + lh * 8;
    f32x4 acc2[4];
#pragma unroll
    for (int nb = 0; nb < 4; ++nb) acc2[nb] = (f32x4){0.f, 0.f, 0.f, 0.f};
#pragma unroll
    for (int kb = 0; kb < 4; ++kb) {
        half8 a = *(const half8*)(mrow + kb * 32);
#pragma unroll
        for (int nb = 0; nb < 4; ++nb) {
            half8 b = *(const half8*)(w2b + nb * 2048 + kb * 32);
            acc2[nb] = __builtin_amdgcn_mfma_f32_16x16x32_f16(a, b, acc2[nb], 0, 0, 0);
        }
    }

    float b2v[4], cps[4] = {0.f, 0.f, 0.f, 0.f};
    float cv[4][4];
#pragma unroll
    for (int nb = 0; nb < 4; ++nb) b2v[nb] = b2[l * 64 + nb * 16 + lm];
#pragma unroll
    for (int nb = 0; nb < 4; ++nb)
#pragma unroll
        for (int r = 0; r < 4; ++r) {
            long ci = (long)(node0 + lh * 4 + r) * 64 + nb * 16 + lm;
            float z = acc2[nb][r] + b2v[nb] + (residual ? cur[ci] : 0.f);
            cur[ci] = z;
            cv[nb][r] = z;
            cps[r] += z;
        }
    if (hh) {
        float gn[4], bn[4], mu[4], rv[4];
        float pvv[4] = {0.f, 0.f, 0.f, 0.f};
#pragma unroll
        for (int nb = 0; nb < 4; ++nb) { gn[nb] = ng[nb * 16 + lm]; bn[nb] = nbv[nb * 16 + lm]; }
#pragma unroll
        for (int r = 0; r < 4; ++r) {
            float s = cps[r];
            for (int off = 1; off < 16; off <<= 1) s += __shfl_xor(s, off, 64);
            mu[r] = s * (1.f / 64.f);
        }
#pragma unroll
        for (int nb = 0; nb < 4; ++nb)
#pragma unroll
            for (int r = 0; r < 4; ++r) { float d = cv[nb][r] - mu[r]; pvv[r] = fmaf(d, d, pvv[r]); }
#pragma unroll
        for (int r = 0; r < 4; ++r) {
            float s = pvv[r];
            for (int off = 1; off < 16; off <<= 1) s += __shfl_xor(s, off, 64);
            rv[r] = rsqrtf(s * (1.f / 64.f) + 1e-5f);
        }
#pragma unroll
        for (int nb = 0; nb < 4; ++nb)
#pragma unroll
            for (int r = 0; r < 4; ++r) {
                long ci = (long)(node0 + lh * 4 + r) * 64 + nb * 16 + lm;
                hh[ci] = __float2half(fmaxf((cv[nb][r] - mu[r]) * rv[r] * gn[nb] + bn[nb], 0.f));
            }
    }
}

// ---------------- pooling (atomic-free, batch sorted) ----------------
__global__ __launch_bounds__(1024) void k_pool2(
    const float* __restrict__ cur, const int* __restrict__ gstart,
    const float* __restrict__ g, const float* __restrict__ b,
    float* __restrict__ out) {
    int gi = blockIdx.x;
    int lane = threadIdx.x & 63, w = threadIdx.x >> 6;
    int s = gstart[gi], e = gstart[gi + 1];
    float gg = g[lane], bb = b[lane];
    float acc = 0.f;
    for (int n = s + w; n < e; n += 16) {
        float v = cur[(long)n * 64 + lane];
        float mu = wave_sum(v) * (1.f / 64.f);
        float d = v - mu;
        float var = wave_sum(d * d) * (1.f / 64.f);
        acc += fmaxf(d * rsqrtf(var + 1e-5f) * gg + bb, 0.f);
    }
    __shared__ float sh[16][64];
    sh[w][lane] = acc;
    __syncthreads();
    if (w == 0) {
        float tot = 0.f;
#pragma unroll
        for (int k = 0; k < 16; ++k) tot += sh[k][lane];
        out[gi * 64 + lane] = tot / fmaxf((float)(e - s), 1.f);
    }
}

extern "C" void kernel_launch(void* const* d_in, const int* in_sizes, int n_in,
                              void* d_out, int out_size, void* d_ws, size_t ws_size,
                              hipStream_t stream) {
    (void)in_sizes; (void)n_in; (void)out_size; (void)ws_size;
    const int* x         = (const int*)d_in[0];
    const int* edge_attr = (const int*)d_in[1];
    const int* src       = (const int*)d_in[2];
    const int* dst       = src + NE;
    const int* batch     = (const int*)d_in[3];
    const float* atom_emb = (const float*)d_in[4];
    const float* bond_emb = (const float*)d_in[5];
    const float* t        = (const float*)d_in[6];
    const float* W1       = (const float*)d_in[7];
    const float* b1       = (const float*)d_in[8];
    const float* g1       = (const float*)d_in[9];
    const float* bb1      = (const float*)d_in[10];
    const float* W2       = (const float*)d_in[11];
    const float* b2       = (const float*)d_in[12];
    const float* norm_g   = (const float*)d_in[13];
    const float* norm_b   = (const float*)d_in[14];
    float* out = (float*)d_out;

    size_t off = 0;
    auto alloc = [&](size_t bytes) {
        void* p = (char*)d_ws + off;
        off += (bytes + 255) & ~(size_t)255;
        return p;
    };
    int*    count  = (int*)alloc((size_t)NN * 4);
    int*    wofs   = (int*)alloc((size_t)NN * 4);
    int*    rowptr = (int*)alloc((size_t)(NN + 1) * 4);
    int*    bsum   = (int*)alloc(4096);
    int*    csr32  = (int*)alloc((size_t)NE * 4);
    __half* comb   = (__half*)alloc(1000 * 64 * 2);
    __half* xnH    = (__half*)alloc((size_t)NN * 64 * 2);
    __half* hhH    = (__half*)alloc((size_t)NN * 64 * 2);
    float*  cur    = (float*)alloc((size_t)NN * 64 * 4);
    int*    gstart = (int*)alloc((size_t)(NG + 1) * 4);
    __half* w1t    = (__half*)alloc((size_t)NL * 8192 * 2);
    __half* w2t    = (__half*)alloc((size_t)NL * 8192 * 2);

    hipMemsetAsync(count, 0, (size_t)NN * 4, stream);
    hipMemsetAsync(wofs, 0, (size_t)NN * 4, stream);

    const int EB = (NE + 255) / 256;
    const int SB = (NN + 255) / 256;
    const int WB = (NN * 64 + 255) / 256;

    k_count<<<EB, 256, 0, stream>>>(dst, count);
    k_scan1<<<SB, 256, 0, stream>>>(count, rowptr + 1, bsum, NN);
    k_scan2<<<1, 256, 0, stream>>>(bsum, SB);
    k_scan3<<<SB, 256, 0, stream>>>(rowptr, bsum, NN);
    k_fill<<<EB * 8, 256, 0, stream>>>(src, dst, edge_attr, rowptr, wofs, csr32);
    k_prep<<<SB, 256, 0, stream>>>(bond_emb, comb, W1, W2, w1t, w2t, batch, gstart);
    k_atom<<<WB, 256, 0, stream>>>(x, atom_emb, xnH);

    // Ping-pong (fused kernel writes next-layer activations while others gather):
    // L0: xnH -> hhH ; L1: hhH -> xnH ; L2: xnH -> hhH ; L3: hhH -> none.
    __half* bufs[2] = {hhH, xnH};
    const int CB = NN / 16;   // 5000 blocks, 4 waves x 4 nodes agg + wave0 MLP
    for (int l = 0; l < NL; ++l) {
        const __half* hin = (l == 0) ? xnH : bufs[(l & 1) ^ 1];
        __half* hh_out = (l < NL - 1) ? bufs[l & 1] : nullptr;
        const float* ngp = norm_g + (l + 1 < NL ? (l + 1) * 64 : 0);
        const float* nbp = norm_b + (l + 1 < NL ? (l + 1) * 64 : 0);
        k_conv<<<CB, 256, 0, stream>>>(hin, rowptr, csr32, comb, t, l,
                                       w1t, w2t, b1, g1, bb1, b2,
                                       cur, l > 0, hh_out, ngp, nbp);
    }
    k_pool2<<<NG, 1024, 0, stream>>>(cur, gstart, norm_g, norm_b, out);
}

// Round 20
// 476.374 us; speedup vs baseline: 1.0933x; 1.0933x over previous
//
#include <hip/hip_runtime.h>
#include <hip/hip_bf16.h>
#include <hip/hip_fp16.h>

#define NN 80000
#define NE 1280000
#define NL 4
#define NG 256

typedef __attribute__((ext_vector_type(8))) _Float16 half8;
typedef __attribute__((ext_vector_type(4))) float f32x4;

__device__ __forceinline__ float wave_sum(float v) {
    for (int off = 32; off; off >>= 1) v += __shfl_xor(v, off, 64);
    return v;
}

// ---------------- CSR build ----------------
__global__ void k_count(const int* __restrict__ idx, int* __restrict__ cnt) {
    int e = blockIdx.x * 256 + threadIdx.x;
    if (e < NE) atomicAdd(&cnt[idx[e]], 1);
}

__global__ void k_scan1(const int* __restrict__ in, int* __restrict__ out,
                        int* __restrict__ bsum, int n) {
    __shared__ int ws[4];
    int i = blockIdx.x * 256 + threadIdx.x;
    int v = (i < n) ? in[i] : 0;
    int lane = threadIdx.x & 63, w = threadIdx.x >> 6;
    for (int off = 1; off < 64; off <<= 1) {
        int t = __shfl_up(v, off, 64);
        if (lane >= off) v += t;
    }
    if (lane == 63) ws[w] = v;
    __syncthreads();
    if (threadIdx.x == 0) {
        int acc = 0;
        for (int k = 0; k < 4; k++) { int t = ws[k]; ws[k] = acc; acc += t; }
    }
    __syncthreads();
    v += ws[w];
    if (i < n) out[i] = v;
    if (threadIdx.x == 255) bsum[blockIdx.x] = v;
}

__global__ void k_scan2(int* __restrict__ bsum, int nb) {
    __shared__ int ws[4];
    __shared__ int carry;
    if (threadIdx.x == 0) carry = 0;
    __syncthreads();
    for (int base = 0; base < nb; base += 256) {
        int i = base + threadIdx.x;
        int v = (i < nb) ? bsum[i] : 0;
        int lane = threadIdx.x & 63, w = threadIdx.x >> 6;
        for (int off = 1; off < 64; off <<= 1) {
            int t = __shfl_up(v, off, 64);
            if (lane >= off) v += t;
        }
        if (lane == 63) ws[w] = v;
        __syncthreads();
        if (threadIdx.x == 0) {
            int acc = carry;
            for (int k = 0; k < 4; k++) { int t = ws[k]; ws[k] = acc; acc += t; }
            carry = acc;
        }
        __syncthreads();
        v += ws[w];
        if (i < nb) bsum[i] = v;
        __syncthreads();
    }
}

__global__ void k_scan3(int* __restrict__ rowptr, const int* __restrict__ bsum, int n) {
    int i = blockIdx.x * 256 + threadIdx.x;
    if (i < n) {
        int off = (blockIdx.x > 0) ? bsum[blockIdx.x - 1] : 0;
        rowptr[1 + i] += off;
    }
    if (i == 0 && blockIdx.x == 0) rowptr[0] = 0;
}

// Partitioned fill: partition p = blockIdx.x & 7 handles dst in [p*10000,(p+1)*10000).
// Round-robin dispatch maps same-p blocks to the same XCD -> csr32 writes stay in an
// L2-resident window (R18: WRITE 86->64MB, dur 81->62us).
__global__ void k_fill(const int* __restrict__ src, const int* __restrict__ dst,
                       const int* __restrict__ eattr, const int* __restrict__ rowptr,
                       int* __restrict__ wofs, int* __restrict__ csr32) {
    int part = blockIdx.x & 7;
    int e = (blockIdx.x >> 3) * 256 + threadIdx.x;
    if (e >= NE) return;
    int d = dst[e];
    if (d / 10000 != part) return;
    int pos = rowptr[d] + atomicAdd(&wofs[d], 1);
    int a0 = eattr[e * 3], a1 = eattr[e * 3 + 1], a2 = eattr[e * 3 + 2];
    csr32[pos] = (src[e] << 10) | (a0 + a1 * 10 + a2 * 100);
}

// ---------------- fused prep: comb + packw + bounds ----------------
__global__ void k_prep(const float* __restrict__ bond_emb, __half* __restrict__ comb,
                       const float* __restrict__ W1, const float* __restrict__ W2,
                       __half* __restrict__ w1t, __half* __restrict__ w2t,
                       const int* __restrict__ batch, int* __restrict__ gstart) {
    int idx = blockIdx.x * 256 + threadIdx.x;
    if (idx < NN) {
        int b = batch[idx];
        if (idx == 0) {
            for (int g = 0; g <= b; ++g) gstart[g] = 0;
        } else {
            int pb = batch[idx - 1];
            for (int g = pb + 1; g <= b; ++g) gstart[g] = idx;
        }
        if (idx == NN - 1) {
            for (int g = b + 1; g <= NG; ++g) gstart[g] = NN;
        }
    }
    if (idx < 64000) {
        int wid = idx >> 6, lane = idx & 63;
        int a0 = wid % 10, a1 = (wid / 10) % 10, a2 = wid / 100;
        comb[wid * 64 + lane] = __float2half(bond_emb[a0 * 64 + lane] +
                                             bond_emb[(10 + a1) * 64 + lane] +
                                             bond_emb[(20 + a2) * 64 + lane]);
    }
    if (idx < NL * 8192) {
        int l = idx >> 13, r = idx & 8191;
        int n1 = r >> 6, k1 = r & 63;
        w1t[idx] = __float2half(W1[(l * 64 + k1) * 128 + n1]);
        int n2 = r >> 7, k2 = r & 127;
        w2t[idx] = __float2half(W2[(l * 128 + k2) * 64 + n2]);
    }
}

__global__ void k_atom(const int* __restrict__ x, const float* __restrict__ atom_emb,
                       __half* __restrict__ xn) {
    int wid = (blockIdx.x * 256 + threadIdx.x) >> 6;
    int lane = threadIdx.x & 63;
    if (wid >= NN) return;
    float acc = 0.f;
#pragma unroll
    for (int f = 0; f < 9; f++) {
        int idx = x[wid * 9 + f] + f * 100;
        acc += atom_emb[idx * 64 + lane];
    }
    xn[wid * 64 + lane] = __float2half(acc);
}

// ---------------- aggregation: 2 nodes/wave, packed fp16 channel pairs ----------------
__global__ __launch_bounds__(256) void k_agg3(
    const __half* __restrict__ hin, const int* __restrict__ rowptr,
    const int* __restrict__ csr32, const __half* __restrict__ comb,
    const float* __restrict__ t, int l, __half* __restrict__ o) {
    int w = blockIdx.x * 4 + (threadIdx.x >> 6);   // NN/2 waves total
    int lane = threadIdx.x & 63;
    int half = lane >> 5, lc = lane & 31;
    int node = w * 2 + half;
    float tl = t[l];
    const __half2* hin2 = (const __half2*)hin;
    const __half2* comb2 = (const __half2*)comb;
    long oi2 = (long)node * 32 + lc;
    __half2 hr2 = hin2[oi2];
    int rs0 = rowptr[w * 2], mid = rowptr[w * 2 + 1], re1 = rowptr[w * 2 + 2];
    int base = half ? mid : rs0;
    int cnt = half ? (re1 - mid) : (mid - rs0);
    int cmax = max(mid - rs0, re1 - mid);
    float den0 = 0.f, den1 = 0.f, num0 = 0.f, num1 = 0.f;
#pragma unroll 4
    for (int i = 0; i < cmax; ++i) {
        bool valid = i < cnt;
        int v = csr32[valid ? base + i : 0];
        __half2 h2 = hin2[(long)(v >> 10) * 32 + lc];
        __half2 c2 = comb2[(v & 1023) * 32 + lc];
        __half2 s2 = __hadd2(h2, c2);
        float m0 = fmaxf(__low2float(s2), 0.f) + 1e-7f;
        float m1 = fmaxf(__high2float(s2), 0.f) + 1e-7f;
        float e0 = valid ? __expf(m0 * tl) : 0.f;
        float e1 = valid ? __expf(m1 * tl) : 0.f;
        den0 += e0; num0 = fmaf(e0, m0, num0);
        den1 += e1; num1 = fmaf(e1, m1, num1);
    }
    float r0 = num0 / (den0 + 1e-16f) + __low2float(hr2);
    float r1 = num1 / (den1 + 1e-16f) + __high2float(hr2);
    ((__half2*)o)[oi2] = __floats2half2_rn(r0, r1);
}

// ---------------- MFMA MLP: 16 nodes/wave, 4 waves/block ----------------
__global__ __launch_bounds__(256) void k_mlp(
    const __half* __restrict__ o, int l,
    const __half* __restrict__ w1t, const __half* __restrict__ w2t,
    const float* __restrict__ b1, const float* __restrict__ g1,
    const float* __restrict__ bb1, const float* __restrict__ b2,
    float* __restrict__ cur, int residual,
    __half* __restrict__ hh, const float* __restrict__ ng, const float* __restrict__ nbv) {
    __shared__ __half midL[4][16][136];
    int w = threadIdx.x >> 6, lane = threadIdx.x & 63;
    int node0 = blockIdx.x * 64 + w * 16;           // NN == 1250*64
    int lm = lane & 15, lh = lane >> 4;

    const __half* ob = o + (long)(node0 + lm) * 64 + lh * 8;
    half8 a0 = *(const half8*)(ob);
    half8 a1 = *(const half8*)(ob + 32);
    const __half* w1b = w1t + l * 8192 + lm * 64 + lh * 8;
    f32x4 acc[8];
#pragma unroll
    for (int nb = 0; nb < 8; ++nb) {
        f32x4 c = {0.f, 0.f, 0.f, 0.f};
        half8 b0 = *(const half8*)(w1b + nb * 1024);
        half8 bx = *(const half8*)(w1b + nb * 1024 + 32);
        c = __builtin_amdgcn_mfma_f32_16x16x32_f16(a0, b0, c, 0, 0, 0);
        c = __builtin_amdgcn_mfma_f32_16x16x32_f16(a1, bx, c, 0, 0, 0);
        acc[nb] = c;
    }

    float bv[8], gv[8], bbv[8];
#pragma unroll
    for (int nb = 0; nb < 8; ++nb) {
        int n = l * 128 + nb * 16 + lm;
        bv[nb] = b1[n]; gv[nb] = g1[n]; bbv[nb] = bb1[n];
    }
    float ps[4] = {0.f, 0.f, 0.f, 0.f};
#pragma unroll
    for (int nb = 0; nb < 8; ++nb)
#pragma unroll
        for (int r = 0; r < 4; ++r) { acc[nb][r] += bv[nb]; ps[r] += acc[nb][r]; }
#pragma unroll
    for (int r = 0; r < 4; ++r) {
        for (int off = 1; off < 16; off <<= 1) ps[r] += __shfl_xor(ps[r], off, 64);
        ps[r] *= (1.f / 128.f);
    }
    float pv[4] = {0.f, 0.f, 0.f, 0.f};
#pragma unroll
    for (int nb = 0; nb < 8; ++nb)
#pragma unroll
        for (int r = 0; r < 4; ++r) { float d = acc[nb][r] - ps[r]; pv[r] = fmaf(d, d, pv[r]); }
#pragma unroll
    for (int r = 0; r < 4; ++r) {
        for (int off = 1; off < 16; off <<= 1) pv[r] += __shfl_xor(pv[r], off, 64);
        pv[r] = rsqrtf(pv[r] * (1.f / 128.f) + 1e-5f);
    }
#pragma unroll
    for (int nb = 0; nb < 8; ++nb)
#pragma unroll
        for (int r = 0; r < 4; ++r) {
            float m = fmaxf((acc[nb][r] - ps[r]) * pv[r] * gv[nb] + bbv[nb], 0.f);
            midL[w][lh * 4 + r][nb * 16 + lm] = __float2half(m);
        }

    const __half* mrow = &midL[w][lm][lh * 8];
    const __half* w2b = w2t + l * 8192 + lm * 128 + lh * 8;
    f32x4 acc2[4];
#pragma unroll
    for (int nb = 0; nb < 4; ++nb) acc2[nb] = (f32x4){0.f, 0.f, 0.f, 0.f};
#pragma unroll
    for (int kb = 0; kb < 4; ++kb) {
        half8 a = *(const half8*)(mrow + kb * 32);
#pragma unroll
        for (int nb = 0; nb < 4; ++nb) {
            half8 b = *(const half8*)(w2b + nb * 2048 + kb * 32);
            acc2[nb] = __builtin_amdgcn_mfma_f32_16x16x32_f16(a, b, acc2[nb], 0, 0, 0);
        }
    }

    float b2v[4], cps[4] = {0.f, 0.f, 0.f, 0.f};
    float cv[4][4];
#pragma unroll
    for (int nb = 0; nb < 4; ++nb) b2v[nb] = b2[l * 64 + nb * 16 + lm];
#pragma unroll
    for (int nb = 0; nb < 4; ++nb)
#pragma unroll
        for (int r = 0; r < 4; ++r) {
            long ci = (long)(node0 + lh * 4 + r) * 64 + nb * 16 + lm;
            float z = acc2[nb][r] + b2v[nb] + (residual ? cur[ci] : 0.f);
            cur[ci] = z;
            cv[nb][r] = z;
            cps[r] += z;
        }
    if (hh) {
        float gn[4], bn[4], mu[4], rv[4];
        float pvv[4] = {0.f, 0.f, 0.f, 0.f};
#pragma unroll
        for (int nb = 0; nb < 4; ++nb) { gn[nb] = ng[nb * 16 + lm]; bn[nb] = nbv[nb * 16 + lm]; }
#pragma unroll
        for (int r = 0; r < 4; ++r) {
            float s = cps[r];
            for (int off = 1; off < 16; off <<= 1) s += __shfl_xor(s, off, 64);
            mu[r] = s * (1.f / 64.f);
        }
#pragma unroll
        for (int nb = 0; nb < 4; ++nb)
#pragma unroll
            for (int r = 0; r < 4; ++r) { float d = cv[nb][r] - mu[r]; pvv[r] = fmaf(d, d, pvv[r]); }
#pragma unroll
        for (int r = 0; r < 4; ++r) {
            float s = pvv[r];
            for (int off = 1; off < 16; off <<= 1) s += __shfl_xor(s, off, 64);
            rv[r] = rsqrtf(s * (1.f / 64.f) + 1e-5f);
        }
#pragma unroll
        for (int nb = 0; nb < 4; ++nb)
#pragma unroll
            for (int r = 0; r < 4; ++r) {
                long ci = (long)(node0 + lh * 4 + r) * 64 + nb * 16 + lm;
                hh[ci] = __float2half(fmaxf((cv[nb][r] - mu[r]) * rv[r] * gn[nb] + bn[nb], 0.f));
            }
    }
}

// ---------------- pooling (atomic-free, batch sorted) ----------------
__global__ __launch_bounds__(1024) void k_pool2(
    const float* __restrict__ cur, const int* __restrict__ gstart,
    const float* __restrict__ g, const float* __restrict__ b,
    float* __restrict__ out) {
    int gi = blockIdx.x;
    int lane = threadIdx.x & 63, w = threadIdx.x >> 6;
    int s = gstart[gi], e = gstart[gi + 1];
    float gg = g[lane], bb = b[lane];
    float acc = 0.f;
    for (int n = s + w; n < e; n += 16) {
        float v = cur[(long)n * 64 + lane];
        float mu = wave_sum(v) * (1.f / 64.f);
        float d = v - mu;
        float var = wave_sum(d * d) * (1.f / 64.f);
        acc += fmaxf(d * rsqrtf(var + 1e-5f) * gg + bb, 0.f);
    }
    __shared__ float sh[16][64];
    sh[w][lane] = acc;
    __syncthreads();
    if (w == 0) {
        float tot = 0.f;
#pragma unroll
        for (int k = 0; k < 16; ++k) tot += sh[k][lane];
        out[gi * 64 + lane] = tot / fmaxf((float)(e - s), 1.f);
    }
}

extern "C" void kernel_launch(void* const* d_in, const int* in_sizes, int n_in,
                              void* d_out, int out_size, void* d_ws, size_t ws_size,
                              hipStream_t stream) {
    (void)in_sizes; (void)n_in; (void)out_size; (void)ws_size;
    const int* x         = (const int*)d_in[0];
    const int* edge_attr = (const int*)d_in[1];
    const int* src       = (const int*)d_in[2];
    const int* dst       = src + NE;
    const int* batch     = (const int*)d_in[3];
    const float* atom_emb = (const float*)d_in[4];
    const float* bond_emb = (const float*)d_in[5];
    const float* t        = (const float*)d_in[6];
    const float* W1       = (const float*)d_in[7];
    const float* b1       = (const float*)d_in[8];
    const float* g1       = (const float*)d_in[9];
    const float* bb1      = (const float*)d_in[10];
    const float* W2       = (const float*)d_in[11];
    const float* b2       = (const float*)d_in[12];
    const float* norm_g   = (const float*)d_in[13];
    const float* norm_b   = (const float*)d_in[14];
    float* out = (float*)d_out;

    size_t off = 0;
    auto alloc = [&](size_t bytes) {
        void* p = (char*)d_ws + off;
        off += (bytes + 255) & ~(size_t)255;
        return p;
    };
    int*    count  = (int*)alloc((size_t)NN * 4);
    int*    wofs   = (int*)alloc((size_t)NN * 4);
    int*    rowptr = (int*)alloc((size_t)(NN + 1) * 4);
    int*    bsum   = (int*)alloc(4096);
    int*    csr32  = (int*)alloc((size_t)NE * 4);
    __half* comb   = (__half*)alloc(1000 * 64 * 2);
    __half* xnH    = (__half*)alloc((size_t)NN * 64 * 2);
    __half* hhH    = (__half*)alloc((size_t)NN * 64 * 2);
    __half* oH     = (__half*)alloc((size_t)NN * 64 * 2);
    float*  cur    = (float*)alloc((size_t)NN * 64 * 4);
    int*    gstart = (int*)alloc((size_t)(NG + 1) * 4);
    __half* w1t    = (__half*)alloc((size_t)NL * 8192 * 2);
    __half* w2t    = (__half*)alloc((size_t)NL * 8192 * 2);

    hipMemsetAsync(count, 0, (size_t)NN * 4, stream);
    hipMemsetAsync(wofs, 0, (size_t)NN * 4, stream);

    const int EB = (NE + 255) / 256;
    const int SB = (NN + 255) / 256;
    const int WB = (NN * 64 + 255) / 256;

    k_count<<<EB, 256, 0, stream>>>(dst, count);
    k_scan1<<<SB, 256, 0, stream>>>(count, rowptr + 1, bsum, NN);
    k_scan2<<<1, 256, 0, stream>>>(bsum, SB);
    k_scan3<<<SB, 256, 0, stream>>>(rowptr, bsum, NN);
    k_fill<<<EB * 8, 256, 0, stream>>>(src, dst, edge_attr, rowptr, wofs, csr32);
    k_prep<<<SB, 256, 0, stream>>>(bond_emb, comb, W1, W2, w1t, w2t, batch, gstart);
    k_atom<<<WB, 256, 0, stream>>>(x, atom_emb, xnH);

    const int AB = NN / 8;    // 10000 blocks: 4 waves x 2 nodes each
    const int MBK = NN / 64;  // 1250 blocks
    for (int l = 0; l < NL; ++l) {
        const __half* hin = (l == 0) ? xnH : hhH;
        __half* hh_out = (l < NL - 1) ? hhH : nullptr;
        const float* ngp = norm_g + (l + 1 < NL ? (l + 1) * 64 : 0);
        const float* nbp = norm_b + (l + 1 < NL ? (l + 1) * 64 : 0);
        k_agg3<<<AB, 256, 0, stream>>>(hin, rowptr, csr32, comb, t, l, oH);
        k_mlp<<<MBK, 256, 0, stream>>>(oH, l, w1t, w2t, b1, g1, bb1, b2,
                                       cur, l > 0, hh_out, ngp, nbp);
    }
    k_pool2<<<NG, 1024, 0, stream>>>(cur, gstart, norm_g, norm_b, out);
}